// Round 12
// baseline (182.831 us; speedup 1.0000x reference)
//
#include <hip/hip_runtime.h>

#define N 8000
#define SEQ 200
#define MAX_STEPS 199
#define DTOT (MAX_STEPS * MAX_STEPS)    // 39601

#define NTH 256
#define NBLK 2048                       // block 0 = loss; 1..2047 = reg
#define GB 155                          // gather blocks = reg-blocks 0..154
#define SBn 1471                        // streaming reg blocks (NT)
#define CBn 576                         // cached reg blocks (L3 slice)
#define STn (SBn * NTH)                 // 376,576
#define CTn (CBn * NTH)                 // 147,456
#define NN4 16000000                    // f4 per matrix
#define S1 11520000                     // stream region [0,S1); cached [S1,NN4)
#define SFULL 30                        // 30*376,576 = 11,297,280; tail 222,720
#define CFULL 30                        // 30*147,456 =  4,423,680; tail  56,320

typedef float f4 __attribute__((ext_vector_type(4)));

__device__ __forceinline__ float log_sum4(f4 v) {
    // log(|x|+1) = ln2 * log2(|x|+1); ln2*0.5 folded at the accumulator add.
    return __log2f(fabsf(v[0]) + 1.0f) + __log2f(fabsf(v[1]) + 1.0f) +
           __log2f(fabsf(v[2]) + 1.0f) + __log2f(fabsf(v[3]) + 1.0f);
}

// ws layout: [0]=gather flag (u32), [1]=done counter (u32), [2]=acc (f32),
//            [3]=pad, [4..]=D (39601 f32). Harness memsets first 16 B / launch.

__global__ void __launch_bounds__(NTH, 8)
k_one(const int* __restrict__ a,
      const float* __restrict__ s,
      const float* __restrict__ pe,
      const float* __restrict__ ne,
      const float* __restrict__ kp,
      unsigned int* __restrict__ wsu,
      float* __restrict__ out) {
    float* accf = (float*)(wsu + 2);
    float* D    = (float*)(wsu + 4);
    __shared__ float wsum[NTH / 64];
    const int tid = threadIdx.x;

    if (blockIdx.x == 0) {
        // ---------------- loss block: wait for D, then scan ----------------
        __shared__ int   sa[MAX_STEPS];
        __shared__ float ss[MAX_STEPS];
        for (int i = tid; i < MAX_STEPS; i += NTH) { sa[i] = a[i]; ss[i] = s[i]; }
        __syncthreads();

        __shared__ int V;
        if (tid == 0) {
            int v = MAX_STEPS;
            for (int t = 0; t < MAX_STEPS; ++t)
                if (ss[t] < 0.0f) { v = t; break; }
            V = v;
            // acquire-poll: gather blocks release-increment after writing D
            while (__hip_atomic_load(&wsu[0], __ATOMIC_ACQUIRE,
                                     __HIP_MEMORY_SCOPE_AGENT) < (unsigned)GB)
                __builtin_amdgcn_s_sleep(2);
        }
        __syncthreads();

        float li = 0.0f;
        if (tid < MAX_STEPS && tid < V) {
            int j = sa[tid];
            float k = kp[j];
            int t = 0;
            for (; t + 8 <= tid; t += 8) {
                float d[8];
                #pragma unroll
                for (int u = 0; u < 8; ++u) d[u] = D[(t + u) * MAX_STEPS + tid];
                #pragma unroll
                for (int u = 0; u < 8; ++u)
                    k = fminf(fmaxf(k + d[u], -30.0f), 30.0f);
            }
            for (; t < tid; ++t)
                k = fminf(fmaxf(k + D[t * MAX_STEPS + tid], -30.0f), 30.0f);
            float p = fminf(fmaxf(k, 0.01f), 0.99f);
            li = -(ss[tid] * logf(p) + (1.0f - ss[tid]) * logf(1.0f - p));
        }

        #pragma unroll
        for (int o = 32; o > 0; o >>= 1) li += __shfl_down(li, o);
        if ((tid & 63) == 0) wsum[tid >> 6] = li;
        __syncthreads();
        if (tid == 0) {
            float total = 0.0f;
            #pragma unroll
            for (int w = 0; w < NTH / 64; ++w) total += wsum[w];
            atomicAdd(accf, total);
            unsigned old = __hip_atomic_fetch_add(&wsu[1], 1u, __ATOMIC_ACQ_REL,
                                                  __HIP_MEMORY_SCOPE_AGENT);
            if (old == NBLK - 1)
                out[0] = __hip_atomic_load(accf, __ATOMIC_RELAXED,
                                           __HIP_MEMORY_SCOPE_AGENT);
        }
        return;
    }

    const int rb = (int)blockIdx.x - 1;     // reg-block index 0..2046

    // -------- gather phase (first GB reg blocks): parallel D scatter -------
    if (rb < GB) {
        __shared__ int   ga[MAX_STEPS];
        __shared__ float gs[MAX_STEPS];
        for (int i = tid; i < MAX_STEPS; i += NTH) { ga[i] = a[i]; gs[i] = s[i]; }
        __syncthreads();
        int idx = rb * NTH + tid;
        if (idx < DTOT) {
            int t = idx / MAX_STEPS;
            int i = idx - t * MAX_STEPS;
            float st = gs[t];
            size_t off = (size_t)ga[t] * N + (size_t)ga[i];
            D[idx] = st * pe[off] + (1.0f - st) * ne[off];
        }
        __syncthreads();
        if (tid == 0) {
            __threadfence();
            __hip_atomic_fetch_add(&wsu[0], 1u, __ATOMIC_RELEASE,
                                   __HIP_MEMORY_SCOPE_AGENT);
        }
    }

    // ------------------------------ regularizer ----------------------------
    const f4* __restrict__ pe4 = (const f4*)pe;
    const f4* __restrict__ ne4 = (const f4*)ne;
    float acc = 0.0f;

    if (rb < SBn) {
        // streaming half: NT dual-stream over [0, S1)
        const int rt = rb * NTH + tid;
        #pragma unroll 2
        for (int k = 0; k < SFULL; ++k) {
            size_t p = (size_t)rt + (size_t)k * STn;
            f4 v = __builtin_nontemporal_load(&pe4[p]);
            f4 w = __builtin_nontemporal_load(&ne4[p]);
            acc += log_sum4(v);
            acc += log_sum4(w);
        }
        {   // tail: rt < 222,720
            size_t p = (size_t)rt + (size_t)SFULL * STn;
            if (p < (size_t)S1) {
                f4 v = __builtin_nontemporal_load(&pe4[p]);
                f4 w = __builtin_nontemporal_load(&ne4[p]);
                acc += log_sum4(v);
                acc += log_sum4(w);
            }
        }
    } else {
        // cached half: L3-resident slice [S1, NN4)
        const int rt = (rb - SBn) * NTH + tid;
        #pragma unroll 2
        for (int k = 0; k < CFULL; ++k) {
            size_t p = (size_t)S1 + (size_t)rt + (size_t)k * CTn;
            f4 v = pe4[p];
            f4 w = ne4[p];
            acc += log_sum4(v);
            acc += log_sum4(w);
        }
        {   // tail: rt < 56,320
            size_t p = (size_t)S1 + (size_t)rt + (size_t)CFULL * CTn;
            if (p < (size_t)NN4) {
                f4 v = pe4[p];
                f4 w = ne4[p];
                acc += log_sum4(v);
                acc += log_sum4(w);
            }
        }
    }

    #pragma unroll
    for (int o = 32; o > 0; o >>= 1) acc += __shfl_down(acc, o);
    if ((tid & 63) == 0) wsum[tid >> 6] = acc;
    __syncthreads();
    if (tid == 0) {
        float b = 0.0f;
        #pragma unroll
        for (int w = 0; w < NTH / 64; ++w) b += wsum[w];
        atomicAdd(accf, 0.34657359027997264f * b);   // 0.5*ln2
        unsigned old = __hip_atomic_fetch_add(&wsu[1], 1u, __ATOMIC_ACQ_REL,
                                              __HIP_MEMORY_SCOPE_AGENT);
        if (old == NBLK - 1)
            out[0] = __hip_atomic_load(accf, __ATOMIC_RELAXED,
                                       __HIP_MEMORY_SCOPE_AGENT);
    }
}

// ---------------- fallback (ws too small): R11 two-kernel path -------------
__global__ void fb_gather(const int* __restrict__ a, const float* __restrict__ s,
                          const float* __restrict__ pe, const float* __restrict__ ne,
                          float* __restrict__ D, float* __restrict__ out) {
    if (blockIdx.x == 0 && threadIdx.x == 0) out[0] = 0.0f;
    __shared__ int sa[MAX_STEPS]; __shared__ float ss[MAX_STEPS];
    for (int i = threadIdx.x; i < MAX_STEPS; i += blockDim.x) { sa[i]=a[i]; ss[i]=s[i]; }
    __syncthreads();
    int idx = blockIdx.x * blockDim.x + threadIdx.x;
    if (idx < DTOT) {
        int t = idx / MAX_STEPS, i = idx - t * MAX_STEPS;
        float st = ss[t];
        size_t off = (size_t)sa[t] * N + (size_t)sa[i];
        D[idx] = st * pe[off] + (1.0f - st) * ne[off];
    }
}

__global__ void __launch_bounds__(NTH)
fb_fused(const int* __restrict__ a, const float* __restrict__ s,
         const float* __restrict__ pe, const float* __restrict__ ne,
         const float* __restrict__ kp, const float* __restrict__ D,
         float* __restrict__ out) {
    __shared__ float wsum[NTH / 64];
    const int tid = threadIdx.x;
    if (blockIdx.x == 0) {
        __shared__ int sa[MAX_STEPS]; __shared__ float ss[MAX_STEPS];
        for (int i = tid; i < MAX_STEPS; i += NTH) { sa[i]=a[i]; ss[i]=s[i]; }
        __syncthreads();
        __shared__ int V;
        if (tid == 0) { int v=MAX_STEPS; for(int t=0;t<MAX_STEPS;++t) if(ss[t]<0.f){v=t;break;} V=v; }
        __syncthreads();
        float li = 0.0f;
        if (tid < MAX_STEPS && tid < V) {
            int j = sa[tid]; float k = kp[j];
            for (int t = 0; t < tid; ++t)
                k = fminf(fmaxf(k + D[t*MAX_STEPS+tid], -30.0f), 30.0f);
            float p = fminf(fmaxf(k, 0.01f), 0.99f);
            li = -(ss[tid]*logf(p) + (1.0f-ss[tid])*logf(1.0f-p));
        }
        #pragma unroll
        for (int o = 32; o > 0; o >>= 1) li += __shfl_down(li, o);
        if ((tid & 63) == 0) wsum[tid >> 6] = li;
        __syncthreads();
        if (tid == 0) { float t2=0; for (int w=0;w<NTH/64;++w) t2+=wsum[w]; atomicAdd(out, t2); }
        return;
    }
    const int rb = (int)blockIdx.x - 1;
    const f4* pe4 = (const f4*)pe; const f4* ne4 = (const f4*)ne;
    float acc = 0.0f;
    const int RT = 2047 * NTH;
    const int rt = rb * NTH + tid;
    #pragma unroll 2
    for (int k = 0; k < 30; ++k) {
        size_t p = (size_t)rt + (size_t)k * RT;
        f4 v = __builtin_nontemporal_load(&pe4[p]);
        f4 w = __builtin_nontemporal_load(&ne4[p]);
        acc += log_sum4(v); acc += log_sum4(w);
    }
    { size_t p = (size_t)rt + (size_t)30 * RT;
      if (p < (size_t)NN4) { f4 v=__builtin_nontemporal_load(&pe4[p]);
                             f4 w=__builtin_nontemporal_load(&ne4[p]);
                             acc += log_sum4(v); acc += log_sum4(w); } }
    #pragma unroll
    for (int o = 32; o > 0; o >>= 1) acc += __shfl_down(acc, o);
    if ((tid & 63) == 0) wsum[tid >> 6] = acc;
    __syncthreads();
    if (tid == 0) { float b=0; for (int w=0;w<NTH/64;++w) b+=wsum[w];
                    atomicAdd(out, 0.34657359027997264f * b); }
}

extern "C" void kernel_launch(void* const* d_in, const int* in_sizes, int n_in,
                              void* d_out, int out_size, void* d_ws, size_t ws_size,
                              hipStream_t stream) {
    const int*   a  = (const int*)d_in[0];
    const float* s  = (const float*)d_in[1];
    const float* pe = (const float*)d_in[2];
    const float* ne = (const float*)d_in[3];
    const float* kp = (const float*)d_in[4];
    float* out = (float*)d_out;

    if (ws_size >= 16 + sizeof(float) * DTOT) {
        unsigned int* wsu = (unsigned int*)d_ws;
        hipMemsetAsync(wsu, 0, 16, stream);   // flag, done, acc, pad
        k_one<<<NBLK, NTH, 0, stream>>>(a, s, pe, ne, kp, wsu, out);
    } else if (ws_size >= sizeof(float) * DTOT) {
        float* D = (float*)d_ws;
        fb_gather<<<(DTOT + NTH - 1) / NTH, NTH, 0, stream>>>(a, s, pe, ne, D, out);
        fb_fused<<<2048, NTH, 0, stream>>>(a, s, pe, ne, kp, D, out);
    }
}

// Round 13
// 86.265 us; speedup vs baseline: 2.1194x; 2.1194x over previous
//
#include <hip/hip_runtime.h>

#define N 8000
#define SEQ 200
#define MAX_STEPS 199

#define REG_THREADS 256
#define SB 1472                         // streaming blocks (NT loads)
#define CB 576                          // cached blocks (L3-resident slice)
#define ST (SB * REG_THREADS)           // 376,832 streaming threads
#define CT (CB * REG_THREADS)           // 147,456 cached threads
#define NN4 16000000                    // f4 per matrix
#define S1 11520000                     // streamed f4 per matrix (first ~184 MB)
#define SFULL 30                        // 30*376,832 = 11,304,960; tail 215,040
#define CFULL 30                        // 30*147,456 =  4,423,680; tail  56,320

typedef float f4 __attribute__((ext_vector_type(4)));

__device__ __forceinline__ float log_sum4(f4 v) {
    // log(|x|+1) = ln2 * log2(|x|+1); ln2*0.5 folded into the final atomic.
    return __log2f(fabsf(v[0]) + 1.0f) + __log2f(fabsf(v[1]) + 1.0f) +
           __log2f(fabsf(v[2]) + 1.0f) + __log2f(fabsf(v[3]) + 1.0f);
}

// -------------------------------------------------------------------------
// K1: zero out; gather D[t][i] = s_t*pe[a_t][a_i] + (1-s_t)*ne[a_t][a_i]
//     into workspace (parallel scatter across 155 blocks; ~2 us).
// -------------------------------------------------------------------------
__global__ void k_init_gather(const int* __restrict__ a,
                              const float* __restrict__ s,
                              const float* __restrict__ pe,
                              const float* __restrict__ ne,
                              float* __restrict__ D, int useD,
                              float* __restrict__ out) {
    if (blockIdx.x == 0 && threadIdx.x == 0) out[0] = 0.0f;
    if (!useD) return;

    __shared__ int   sa[MAX_STEPS];
    __shared__ float ss[MAX_STEPS];
    for (int i = threadIdx.x; i < MAX_STEPS; i += blockDim.x) {
        sa[i] = a[i];
        ss[i] = s[i];
    }
    __syncthreads();

    int idx = blockIdx.x * blockDim.x + threadIdx.x;
    const int total = MAX_STEPS * MAX_STEPS;
    if (idx < total) {
        int t = idx / MAX_STEPS;
        int i = idx - t * MAX_STEPS;
        float st = ss[t];
        size_t off = (size_t)sa[t] * N + (size_t)sa[i];
        float d = st * pe[off] + (1.0f - st) * ne[off];
        D[idx] = d;
    }
}

// -------------------------------------------------------------------------
// K2 (fused): block 0 = sequential loss from D (L2-hot right after K1,
//     coalesced; hidden under the reg stream). Blocks 1..SB+CB = reg:
//     NT dual-stream [0,S1) -> HBM; cached dual-stream [S1,16M) -> L3.
//     512 MB at ~6.1 TB/s aggregate = 97% of measured read ceiling.
//     NO device-scope atomics/fences: R12 proved per-block agent-scope
//     release/acquire (L2 writeback+invalidate on non-coherent XCDs)
//     costs ~100 us at this block count.
// -------------------------------------------------------------------------
__global__ void __launch_bounds__(REG_THREADS)
k_fused(const int* __restrict__ a,
        const float* __restrict__ s,
        const float* __restrict__ pe,
        const float* __restrict__ ne,
        const float* __restrict__ kp,
        const float* __restrict__ D, int useD,
        float* __restrict__ out) {
    __shared__ float wsum[REG_THREADS / 64];
    const int tid = threadIdx.x;

    if (blockIdx.x == 0) {
        // ---------------- loss block (reads dense D, not pe/ne) ------------
        __shared__ int   sa[MAX_STEPS];
        __shared__ float ss[MAX_STEPS];
        for (int i = tid; i < MAX_STEPS; i += REG_THREADS) {
            sa[i] = a[i];
            ss[i] = s[i];
        }
        __syncthreads();

        __shared__ int V;
        if (tid == 0) {
            int v = MAX_STEPS;
            for (int t = 0; t < MAX_STEPS; ++t)
                if (ss[t] < 0.0f) { v = t; break; }
            V = v;
        }
        __syncthreads();

        float li = 0.0f;
        if (tid < MAX_STEPS && tid < V) {
            int j = sa[tid];
            float k = kp[j];
            if (useD) {
                int t = 0;
                for (; t + 8 <= tid; t += 8) {
                    float d[8];
                    #pragma unroll
                    for (int u = 0; u < 8; ++u) d[u] = D[(t + u) * MAX_STEPS + tid];
                    #pragma unroll
                    for (int u = 0; u < 8; ++u)
                        k = fminf(fmaxf(k + d[u], -30.0f), 30.0f);
                }
                for (; t < tid; ++t) {
                    float d = D[t * MAX_STEPS + tid];
                    k = fminf(fmaxf(k + d, -30.0f), 30.0f);
                }
            } else {
                for (int t = 0; t < tid; ++t) {
                    float st = ss[t];
                    size_t off = (size_t)sa[t] * N + (size_t)j;
                    float d = st * pe[off] + (1.0f - st) * ne[off];
                    k = fminf(fmaxf(k + d, -30.0f), 30.0f);
                }
            }
            float p = fminf(fmaxf(k, 0.01f), 0.99f);
            li = -(ss[tid] * logf(p) + (1.0f - ss[tid]) * logf(1.0f - p));
        }

        #pragma unroll
        for (int o = 32; o > 0; o >>= 1) li += __shfl_down(li, o);
        if ((tid & 63) == 0) wsum[tid >> 6] = li;
        __syncthreads();
        if (tid == 0) {
            float total = 0.0f;
            #pragma unroll
            for (int w = 0; w < REG_THREADS / 64; ++w) total += wsum[w];
            atomicAdd(out, total);
        }
        return;
    }

    // --------------------------- regularizer -------------------------------
    const f4* __restrict__ pe4 = (const f4*)pe;
    const f4* __restrict__ ne4 = (const f4*)ne;
    const int rb = (int)blockIdx.x - 1;

    float acc = 0.0f;

    if (rb < SB) {
        // ---------------- streaming half (NT, R6 shape) --------------------
        const int rt = rb * REG_THREADS + tid;
        #pragma unroll 2
        for (int k = 0; k < SFULL; ++k) {
            size_t p = (size_t)rt + (size_t)k * ST;
            f4 v = __builtin_nontemporal_load(&pe4[p]);
            f4 w = __builtin_nontemporal_load(&ne4[p]);
            acc += log_sum4(v);
            acc += log_sum4(w);
        }
        {   // tail: rt < 215,040
            size_t p = (size_t)rt + (size_t)SFULL * ST;
            if (p < (size_t)S1) {
                f4 v = __builtin_nontemporal_load(&pe4[p]);
                f4 w = __builtin_nontemporal_load(&ne4[p]);
                acc += log_sum4(v);
                acc += log_sum4(w);
            }
        }
    } else {
        // ---------------- cached half (L3-resident slice) ------------------
        const int rt = (rb - SB) * REG_THREADS + tid;
        #pragma unroll 2
        for (int k = 0; k < CFULL; ++k) {
            size_t p = (size_t)S1 + (size_t)rt + (size_t)k * CT;
            f4 v = pe4[p];
            f4 w = ne4[p];
            acc += log_sum4(v);
            acc += log_sum4(w);
        }
        {   // tail: rt < 56,320
            size_t p = (size_t)S1 + (size_t)rt + (size_t)CFULL * CT;
            if (p < (size_t)NN4) {
                f4 v = pe4[p];
                f4 w = ne4[p];
                acc += log_sum4(v);
                acc += log_sum4(w);
            }
        }
    }

    // wave64 reduce
    #pragma unroll
    for (int o = 32; o > 0; o >>= 1) acc += __shfl_down(acc, o);
    if ((tid & 63) == 0) wsum[tid >> 6] = acc;
    __syncthreads();
    if (tid == 0) {
        float b = 0.0f;
        #pragma unroll
        for (int w = 0; w < REG_THREADS / 64; ++w) b += wsum[w];
        // 0.5 * ln(2) folded here (log2 -> ln conversion)
        atomicAdd(out, 0.34657359027997264f * b);
    }
}

extern "C" void kernel_launch(void* const* d_in, const int* in_sizes, int n_in,
                              void* d_out, int out_size, void* d_ws, size_t ws_size,
                              hipStream_t stream) {
    const int*   a  = (const int*)d_in[0];
    const float* s  = (const float*)d_in[1];
    const float* pe = (const float*)d_in[2];
    const float* ne = (const float*)d_in[3];
    const float* kp = (const float*)d_in[4];
    float* out = (float*)d_out;

    float* D = (float*)d_ws;
    int useD = (ws_size >= sizeof(float) * MAX_STEPS * MAX_STEPS) ? 1 : 0;

    const int gatherBlocks = (MAX_STEPS * MAX_STEPS + 255) / 256;
    k_init_gather<<<gatherBlocks, 256, 0, stream>>>(a, s, pe, ne, D, useD, out);
    k_fused<<<SB + CB + 1, REG_THREADS, 0, stream>>>(a, s, pe, ne, kp, D, useD, out);
}